// Round 10
// baseline (110.539 us; speedup 1.0000x reference)
//
#include <hip/hip_runtime.h>
#include <hip/hip_bf16.h>

#define VOCAB 50000
#define HID   256
#define BATCH 512
#define GH    768   // 3*H

typedef __attribute__((ext_vector_type(8))) __bf16 bf16x8;
typedef __attribute__((ext_vector_type(4))) float f32x4;
typedef __attribute__((ext_vector_type(4))) unsigned int u32x4;

union BFrag {
    bf16x8 v;
    u32x4  q;
    __bf16 b[8];
};

__device__ __forceinline__ float fast_sigmoid(float x) {
    return 1.0f / (1.0f + __expf(-x));
}
__device__ __forceinline__ float fast_tanh(float x) {
    return 1.0f - 2.0f / (1.0f + __expf(2.0f * x));
}

// 8 consecutive f32 -> one bf16x8 fragment via native casts.
__device__ __forceinline__ void cvt8(BFrag& t, f32x4 lo, f32x4 hi) {
    t.b[0] = (__bf16)lo.x; t.b[1] = (__bf16)lo.y;
    t.b[2] = (__bf16)lo.z; t.b[3] = (__bf16)lo.w;
    t.b[4] = (__bf16)hi.x; t.b[5] = (__bf16)hi.y;
    t.b[6] = (__bf16)hi.z; t.b[7] = (__bf16)hi.w;
}

// ---------------------------------------------------------------------------
// Fragment-ordered A (proven correct in R5/R6): frag fid = (mt*8+kk)*64 + lane,
// 16B each;  row = mt*16 + (lane&15),  k = kk*32 + (lane>>4)*8 + e.
// A wave's frag load = base + lane*16B -> one coalesced 1KB L2 transaction.
// ---------------------------------------------------------------------------

// K0: repack f32 [M][256] row-major -> fragment-ordered bf16. One frag/thread.
__global__ __launch_bounds__(256) void repack_f32(
    const float* __restrict__ src, u32x4* __restrict__ dst, int nFrag)
{
    int fid = blockIdx.x * 256 + threadIdx.x;
    if (fid >= nFrag) return;
    int r = fid & 15, g = (fid >> 4) & 3, kk = (fid >> 6) & 7, mt = fid >> 9;
    const f32x4* p = reinterpret_cast<const f32x4*>(
        src + (size_t)(mt * 16 + r) * 256 + kk * 32 + g * 8);
    BFrag t; cvt8(t, p[0], p[1]);
    dst[fid] = t.q;
}

// GEMM: C = A @ B^T. A fragment-ordered bf16 (L2-resident), B [Ncols][256] f32.
// NO LDS, NO barriers. 512 threads = 8 waves; wave owns 32 cols (2 B-sets of
// 16, 64 VGPR, pinned). Loop over mChunks 32-row chunks: 16 coalesced A-frag
// loads, each feeding 2 MFMAs (A-reuse=2 -> L2 traffic halved), 32 MFMA,
// 16 stores. Block tile = 256 cols; grid.y = M-split (B refetch L3-served).
// EPI 0: raw f32 store   1: tanh(acc + bias[col])
template <int EPI>
__global__ __launch_bounds__(512, 2) void gemm_direct(
    const u32x4* __restrict__ Af, const float* __restrict__ Bm,
    float* __restrict__ C, const float* __restrict__ bias,
    int Ncols, int mChunks)
{
    const int tid  = threadIdx.x;
    const int wid  = tid >> 6;                 // 0..7
    const int lane = tid & 63;
    const int r    = lane & 15;
    const int g    = lane >> 4;
    const int colbase = blockIdx.x * 256 + wid * 32;

    // ---- B fragments: 2 col-sets x 8 k-steps, convert once, pin ----
    BFrag bf[2][8];
    float biasv[2] = {0.f, 0.f};
    #pragma unroll
    for (int n = 0; n < 2; n++) {
        int col  = colbase + n * 16 + r;
        int bcol = col < Ncols ? col : (Ncols - 1);
        const f32x4* wrow = reinterpret_cast<const f32x4*>(Bm + (size_t)bcol * 256);
        #pragma unroll
        for (int kk = 0; kk < 8; kk++)
            cvt8(bf[n][kk], wrow[kk * 8 + g * 2], wrow[kk * 8 + g * 2 + 1]);
        if (EPI == 1) biasv[n] = bias[bcol];
    }
    #pragma unroll
    for (int n = 0; n < 2; n++)
        #pragma unroll
        for (int kk = 0; kk < 8; kk++)
            asm volatile("" : "+v"(bf[n][kk].q));   // keep resident (R5 lesson)

    const int rows0 = blockIdx.y * (mChunks * 32);

    for (int c = 0; c < mChunks; c++) {
        const int mt0 = (rows0 >> 4) + c * 2;       // 2 mt-groups = 32 rows
        const u32x4* a0 = Af + (size_t)(mt0 * 8) * 64 + lane;
        const u32x4* a1 = Af + (size_t)((mt0 + 1) * 8) * 64 + lane;

        f32x4 acc[2][2];
        #pragma unroll
        for (int m = 0; m < 2; m++) {
            acc[m][0] = (f32x4){0.f, 0.f, 0.f, 0.f};
            acc[m][1] = (f32x4){0.f, 0.f, 0.f, 0.f};
        }

        #pragma unroll
        for (int kk = 0; kk < 8; kk++) {
            BFrag af0, af1;
            af0.q = a0[kk * 64];                    // coalesced 1KB
            af1.q = a1[kk * 64];
            acc[0][0] = __builtin_amdgcn_mfma_f32_16x16x32_bf16(af0.v, bf[0][kk].v, acc[0][0], 0, 0, 0);
            acc[0][1] = __builtin_amdgcn_mfma_f32_16x16x32_bf16(af0.v, bf[1][kk].v, acc[0][1], 0, 0, 0);
            acc[1][0] = __builtin_amdgcn_mfma_f32_16x16x32_bf16(af1.v, bf[0][kk].v, acc[1][0], 0, 0, 0);
            acc[1][1] = __builtin_amdgcn_mfma_f32_16x16x32_bf16(af1.v, bf[1][kk].v, acc[1][1], 0, 0, 0);
        }

        const int rowb = rows0 + c * 32 + g * 4;
        #pragma unroll
        for (int m = 0; m < 2; m++) {
            #pragma unroll
            for (int n = 0; n < 2; n++) {
                int col = colbase + n * 16 + r;
                if (col < Ncols) {
                    #pragma unroll
                    for (int j = 0; j < 4; j++) {
                        float v = acc[m][n][j];
                        if (EPI == 1) v = fast_tanh(v + biasv[n]);
                        C[(size_t)(rowb + m * 16 + j) * Ncols + col] = v;
                    }
                }
            }
        }
    }
}

// K2: GRU gates. One block per batch row, thread = k. Writes h1 (f32, d_out
// tail) and h1 in fragment-ordered bf16 (K3's A operand).
__global__ __launch_bounds__(256) void gru_gate(
    const int* __restrict__ inp, const float* __restrict__ hidden,
    const float* __restrict__ w_ih, const float* __restrict__ b_ih,
    const float* __restrict__ b_hh, const float* __restrict__ hproj,
    float* __restrict__ h1out, unsigned short* __restrict__ h1frag)
{
    const int b = blockIdx.x;
    const int k = threadIdx.x;
    const int c = inp[b];

    float xr = w_ih[(size_t)k * VOCAB + c]         + b_ih[k];
    float xz = w_ih[(size_t)(k + 256) * VOCAB + c] + b_ih[k + 256];
    float xn = w_ih[(size_t)(k + 512) * VOCAB + c] + b_ih[k + 512];

    float hr = hproj[b * GH + k]       + b_hh[k];
    float hz = hproj[b * GH + 256 + k] + b_hh[k + 256];
    float hn = hproj[b * GH + 512 + k] + b_hh[k + 512];

    float rg = fast_sigmoid(xr + hr);
    float zg = fast_sigmoid(xz + hz);
    float ng = fast_tanh(xn + rg * hn);
    float h0 = hidden[b * HID + k];
    float h1 = (1.0f - zg) * ng + zg * h0;

    h1out[b * HID + k] = h1;

    // fragment-ordered bf16 write
    int mt = b >> 4, rr = b & 15;
    int kk = k >> 5, gg = (k >> 3) & 3, e = k & 7;
    size_t fid = (size_t)((mt * 8 + kk) * 4 + gg) * 16 + rr;
    __bf16 hb = (__bf16)h1;
    h1frag[fid * 8 + e] = __builtin_bit_cast(unsigned short, hb);
}

extern "C" void kernel_launch(void* const* d_in, const int* in_sizes, int n_in,
                              void* d_out, int out_size, void* d_ws, size_t ws_size,
                              hipStream_t stream) {
    const int*   input  = (const int*)  d_in[0];
    // d_in[1] = target (unused)
    const float* hidden = (const float*)d_in[2];
    const float* w_ih   = (const float*)d_in[3];
    const float* w_hh   = (const float*)d_in[4];
    const float* b_ih   = (const float*)d_in[5];
    const float* b_hh   = (const float*)d_in[6];
    const float* w_out  = (const float*)d_in[7];
    const float* b_out  = (const float*)d_in[8];

    float* logit = (float*)d_out;                            // [512, 50000]
    float* h1    = (float*)d_out + (size_t)BATCH * VOCAB;    // [512, 256]

    u32x4* hfrag  = (u32x4*)d_ws;                                  // 256 KB
    u32x4* h1frag = (u32x4*)((char*)d_ws + 256 * 1024);            // 256 KB
    float* hproj  = (float*)((char*)d_ws + 512 * 1024);           // 1.5 MB

    const int nFrag = BATCH * HID / 8;   // 16384

    // K0: hidden -> fragment-ordered bf16
    repack_f32<<<nFrag / 256, 256, 0, stream>>>(hidden, hfrag, nFrag);

    // K1: hproj = h0 @ w_hh^T  (512 x 768) — grid (3,16), 32-row blocks
    dim3 g1((GH + 255) / 256, 16);
    gemm_direct<0><<<g1, 512, 0, stream>>>(hfrag, w_hh, hproj, nullptr, GH, 1);

    // K2: gates -> h1 (f32) + h1frag (fragment-ordered bf16)
    gru_gate<<<BATCH, 256, 0, stream>>>(input, hidden, w_ih, b_ih, b_hh, hproj,
                                        h1, (unsigned short*)h1frag);

    // K3: logit = tanh(h1 @ w_out^T + b_out) — grid (196,4), 128-row blocks
    dim3 g3((VOCAB + 255) / 256, 4);
    gemm_direct<1><<<g3, 512, 0, stream>>>(h1frag, w_out, logit, b_out, VOCAB, 4);
}

// Round 11
// 101.038 us; speedup vs baseline: 1.0940x; 1.0940x over previous
//
#include <hip/hip_runtime.h>
#include <hip/hip_bf16.h>

#define VOCAB 50000
#define HID   256
#define BATCH 512
#define GH    768   // 3*H

typedef __attribute__((ext_vector_type(8))) __bf16 bf16x8;
typedef __attribute__((ext_vector_type(4))) float f32x4;
typedef __attribute__((ext_vector_type(4))) unsigned int u32x4;

union BFrag {
    bf16x8 v;
    u32x4  q;
    __bf16 b[8];
};

__device__ __forceinline__ float fast_sigmoid(float x) {
    return 1.0f / (1.0f + __expf(-x));
}
__device__ __forceinline__ float fast_tanh(float x) {
    return 1.0f - 2.0f / (1.0f + __expf(2.0f * x));
}

// 8 consecutive f32 -> one bf16x8 fragment via native casts.
__device__ __forceinline__ void cvt8(BFrag& t, f32x4 lo, f32x4 hi) {
    t.b[0] = (__bf16)lo.x; t.b[1] = (__bf16)lo.y;
    t.b[2] = (__bf16)lo.z; t.b[3] = (__bf16)lo.w;
    t.b[4] = (__bf16)hi.x; t.b[5] = (__bf16)hi.y;
    t.b[6] = (__bf16)hi.z; t.b[7] = (__bf16)hi.w;
}

// ---------------------------------------------------------------------------
// Fragment-ordered A (verified R5/R6/R10): frag fid = (mt*8+kk)*64 + lane,
// 16B each;  row = mt*16 + (lane&15),  k = kk*32 + (lane>>4)*8 + e.
// Wave frag load = base + lane*16B -> one coalesced 1KB transaction, and the
// same addresses are read by all 4 waves and all blocks -> L1/L2 broadcast.
// ---------------------------------------------------------------------------

// K0: repack f32 [M][256] row-major -> fragment-ordered bf16. One frag/thread.
__global__ __launch_bounds__(256) void repack_f32(
    const float* __restrict__ src, u32x4* __restrict__ dst, int nFrag)
{
    int fid = blockIdx.x * 256 + threadIdx.x;
    if (fid >= nFrag) return;
    int r = fid & 15, g = (fid >> 4) & 3, kk = (fid >> 6) & 7, mt = fid >> 9;
    const f32x4* p = reinterpret_cast<const f32x4*>(
        src + (size_t)(mt * 16 + r) * 256 + kk * 32 + g * 8);
    BFrag t; cvt8(t, p[0], p[1]);
    dst[fid] = t.q;
}

// Pure-stream GEMM: C = A @ B^T. A fragment-ordered bf16 (L2/L1-resident),
// B [Ncols][256] f32 read once (NT). NO LDS, NO barriers, NO inter-wave
// coupling. 4 waves x 16 cols = 64-col tile; per-wave B-state = 8 frags
// (32 VGPR -> reliably resident, R1/R8). Loop: mChunks x 32 rows, each
// {16 coalesced A-frag loads, 16 MFMA, 8 stores}. launch_bounds(256,6):
// VGPR cap 85 -> ~24 waves/CU of independent streams (fill-kernel regime).
// EPI 0: raw f32 store   1: tanh(acc + bias[col]) + NT store
template <int EPI>
__global__ __launch_bounds__(256, 6) void gemm_stream(
    const u32x4* __restrict__ Af, const float* __restrict__ Bm,
    float* __restrict__ C, const float* __restrict__ bias,
    int Ncols, int mChunks)
{
    const int tid  = threadIdx.x;
    const int wid  = tid >> 6;
    const int lane = tid & 63;
    const int r    = lane & 15;
    const int g    = lane >> 4;
    const int col  = blockIdx.x * 64 + wid * 16 + r;
    const int bcol = col < Ncols ? col : (Ncols - 1);

    // ---- B fragments: 8 per wave (32 VGPR), NT load + convert once ----
    BFrag bf[8];
    {
        const f32x4* wrow = reinterpret_cast<const f32x4*>(Bm + (size_t)bcol * 256);
        #pragma unroll
        for (int kk = 0; kk < 8; kk++) {
            f32x4 lo = __builtin_nontemporal_load(&wrow[kk * 8 + g * 2]);
            f32x4 hi = __builtin_nontemporal_load(&wrow[kk * 8 + g * 2 + 1]);
            cvt8(bf[kk], lo, hi);
        }
    }
    #pragma unroll
    for (int kk = 0; kk < 8; kk++)
        asm volatile("" : "+v"(bf[kk].q));    // keep resident
    float biasv = 0.0f;
    if (EPI == 1) biasv = bias[bcol];

    const int rows0 = blockIdx.y * mChunks * 32;
    const u32x4* abase = Af + (size_t)(rows0 >> 4) * 8 * 64 + lane;

    for (int c = 0; c < mChunks; c++) {
        const u32x4* a0 = abase + (size_t)(c * 2) * 8 * 64;
        const u32x4* a1 = a0 + 8 * 64;

        f32x4 acc0 = (f32x4){0.f, 0.f, 0.f, 0.f};
        f32x4 acc1 = (f32x4){0.f, 0.f, 0.f, 0.f};

        #pragma unroll
        for (int kk = 0; kk < 8; kk++) {
            BFrag a; a.q = a0[kk * 64];         // coalesced 1KB, L1/L2-hit
            acc0 = __builtin_amdgcn_mfma_f32_16x16x32_bf16(a.v, bf[kk].v, acc0, 0, 0, 0);
        }
        #pragma unroll
        for (int kk = 0; kk < 8; kk++) {
            BFrag a; a.q = a1[kk * 64];
            acc1 = __builtin_amdgcn_mfma_f32_16x16x32_bf16(a.v, bf[kk].v, acc1, 0, 0, 0);
        }

        if (col < Ncols) {
            const int rowb = rows0 + c * 32 + g * 4;
            #pragma unroll
            for (int j = 0; j < 4; j++) {
                float v0 = acc0[j];
                float v1 = acc1[j];
                if (EPI == 1) {
                    v0 = fast_tanh(v0 + biasv);
                    v1 = fast_tanh(v1 + biasv);
                    __builtin_nontemporal_store(v0, &C[(size_t)(rowb + j) * Ncols + col]);
                    __builtin_nontemporal_store(v1, &C[(size_t)(rowb + 16 + j) * Ncols + col]);
                } else {
                    C[(size_t)(rowb + j) * Ncols + col]      = v0;
                    C[(size_t)(rowb + 16 + j) * Ncols + col] = v1;
                }
            }
        }
    }
}

// K2: GRU gates. One block per batch row, thread = k. Writes h1 (f32, d_out
// tail) and h1 in fragment-ordered bf16 (K3's A operand).
__global__ __launch_bounds__(256) void gru_gate(
    const int* __restrict__ inp, const float* __restrict__ hidden,
    const float* __restrict__ w_ih, const float* __restrict__ b_ih,
    const float* __restrict__ b_hh, const float* __restrict__ hproj,
    float* __restrict__ h1out, unsigned short* __restrict__ h1frag)
{
    const int b = blockIdx.x;
    const int k = threadIdx.x;
    const int c = inp[b];

    float xr = w_ih[(size_t)k * VOCAB + c]         + b_ih[k];
    float xz = w_ih[(size_t)(k + 256) * VOCAB + c] + b_ih[k + 256];
    float xn = w_ih[(size_t)(k + 512) * VOCAB + c] + b_ih[k + 512];

    float hr = hproj[b * GH + k]       + b_hh[k];
    float hz = hproj[b * GH + 256 + k] + b_hh[k + 256];
    float hn = hproj[b * GH + 512 + k] + b_hh[k + 512];

    float rg = fast_sigmoid(xr + hr);
    float zg = fast_sigmoid(xz + hz);
    float ng = fast_tanh(xn + rg * hn);
    float h0 = hidden[b * HID + k];
    float h1 = (1.0f - zg) * ng + zg * h0;

    h1out[b * HID + k] = h1;

    // fragment-ordered bf16 write
    int mt = b >> 4, rr = b & 15;
    int kk = k >> 5, gg = (k >> 3) & 3, e = k & 7;
    size_t fid = (size_t)((mt * 8 + kk) * 4 + gg) * 16 + rr;
    __bf16 hb = (__bf16)h1;
    h1frag[fid * 8 + e] = __builtin_bit_cast(unsigned short, hb);
}

extern "C" void kernel_launch(void* const* d_in, const int* in_sizes, int n_in,
                              void* d_out, int out_size, void* d_ws, size_t ws_size,
                              hipStream_t stream) {
    const int*   input  = (const int*)  d_in[0];
    // d_in[1] = target (unused)
    const float* hidden = (const float*)d_in[2];
    const float* w_ih   = (const float*)d_in[3];
    const float* w_hh   = (const float*)d_in[4];
    const float* b_ih   = (const float*)d_in[5];
    const float* b_hh   = (const float*)d_in[6];
    const float* w_out  = (const float*)d_in[7];
    const float* b_out  = (const float*)d_in[8];

    float* logit = (float*)d_out;                            // [512, 50000]
    float* h1    = (float*)d_out + (size_t)BATCH * VOCAB;    // [512, 256]

    u32x4* hfrag  = (u32x4*)d_ws;                                  // 256 KB
    u32x4* h1frag = (u32x4*)((char*)d_ws + 256 * 1024);            // 256 KB
    float* hproj  = (float*)((char*)d_ws + 512 * 1024);           // 1.5 MB

    const int nFrag = BATCH * HID / 8;   // 16384

    // K0: hidden -> fragment-ordered bf16
    repack_f32<<<nFrag / 256, 256, 0, stream>>>(hidden, hfrag, nFrag);

    // K1: hproj = h0 @ w_hh^T  (512 x 768) — grid (12, 8), 64-row blocks
    dim3 g1(GH / 64, 8);
    gemm_stream<0><<<g1, 256, 0, stream>>>(hfrag, w_hh, hproj, nullptr, GH, 2);

    // K2: gates -> h1 (f32) + h1frag (fragment-ordered bf16)
    gru_gate<<<BATCH, 256, 0, stream>>>(input, hidden, w_ih, b_ih, b_hh, hproj,
                                        h1, (unsigned short*)h1frag);

    // K3: logit = tanh(h1 @ w_out^T + b_out) — 782 col-blocks, full M stream
    dim3 g3((VOCAB + 63) / 64, 1);
    gemm_stream<1><<<g3, 256, 0, stream>>>(h1frag, w_out, logit, b_out, VOCAB, 16);
}

// Round 12
// 73.974 us; speedup vs baseline: 1.4943x; 1.3659x over previous
//
#include <hip/hip_runtime.h>
#include <hip/hip_bf16.h>

#define VOCAB 50000
#define HID   256
#define BATCH 512
#define GH    768   // 3*H

typedef __attribute__((ext_vector_type(8)))  __bf16 bf16x8;
typedef __attribute__((ext_vector_type(4)))  float  f32x4;
typedef __attribute__((ext_vector_type(16))) float  f32x16;
typedef __attribute__((ext_vector_type(4)))  unsigned int u32x4;

union BFrag {
    bf16x8 v;
    u32x4  q;
    __bf16 b[8];
};

__device__ __forceinline__ float fast_sigmoid(float x) {
    return 1.0f / (1.0f + __expf(-x));
}
__device__ __forceinline__ float fast_tanh(float x) {
    return 1.0f - 2.0f / (1.0f + __expf(2.0f * x));
}

// 8 consecutive f32 -> one bf16x8 fragment via native casts.
__device__ __forceinline__ void cvt8(BFrag& t, f32x4 lo, f32x4 hi) {
    t.b[0] = (__bf16)lo.x; t.b[1] = (__bf16)lo.y;
    t.b[2] = (__bf16)lo.z; t.b[3] = (__bf16)lo.w;
    t.b[4] = (__bf16)hi.x; t.b[5] = (__bf16)hi.y;
    t.b[6] = (__bf16)hi.z; t.b[7] = (__bf16)hi.w;
}

// C[M x NCOLS] = A[M x 256] @ Bm[NCOLS x 256]^T   (K=256 whole, no K-loop)
// 32x32x16 MFMA, 32 cols/wave -> B = 16 frags = 64 VGPR resident per wave
// (2x col coverage of R8 halves total A-ingest: every wave must read all of
// A; fewer col-waves = less traffic). 4 waves = 128-col block. A staged in
// 32-row chunks via double-buffered swizzled LDS (R8-proven write pattern;
// 32x32 read pattern lands 2 lanes/bank = conflict-free). Single raw
// s_barrier per chunk; stores never drained in-loop. launch_bounds(256,4)
// = hard 128-VGPR cap (spill watch: est. ~115). Template-const strides.
// A-frag: lane: row = lane&31, k = ks*16 + (lane>>5)*8 + e
// B-frag: lane: col = lane&31, same k.   C/D: col = lane&31,
// row = (reg&3) + 8*(reg>>2) + 4*(lane>>5)   [guide m74/m101]
// EPI 0: raw f32 store  1: tanh(acc + bias[col]).  ASRC 0: f32 A  1: bf16 A
template <int EPI, int NCOLS, int MCHUNKS, int ASRC>
__global__ __launch_bounds__(256, 4) void gemm32(
    const void* __restrict__ Asrc, const float* __restrict__ Bm,
    float* __restrict__ C, const float* __restrict__ bias)
{
    __shared__ char ldsA[2][32 * 512];        // 2 x (32 rows x 256 bf16), swizzled

    const int tid  = threadIdx.x;
    const int wid  = tid >> 6;
    const int lane = tid & 63;
    const int cw   = lane & 31;               // A-row / B-col / C-col index
    const int h    = lane >> 5;               // k-half
    const int col  = blockIdx.x * 128 + wid * 32 + cw;
    const int bcol = col < NCOLS ? col : (NCOLS - 1);

    // ---- B: 16 frags (64 VGPR), load + convert once, pin ----
    BFrag bf[16];
    {
        const f32x4* wrow = reinterpret_cast<const f32x4*>(Bm + (size_t)bcol * 256);
        #pragma unroll
        for (int ks = 0; ks < 16; ks++)
            cvt8(bf[ks], wrow[ks * 4 + h * 2], wrow[ks * 4 + h * 2 + 1]);
    }
    #pragma unroll
    for (int ks = 0; ks < 16; ks++)
        asm volatile("" : "+v"(bf[ks].q));    // keep resident
    float biasv = 0.0f;
    if (EPI == 1) biasv = bias[bcol];

    // ---- staging: loads lead by 2 chunks, ds_writes by 1 (R8 pattern) ----
    u32x4 areg[4];
    auto load_chunk = [&](int c) {
        const int mbase = (blockIdx.y * MCHUNKS + c) * 32;
        if (ASRC == 1) {
            const u32x4* src = reinterpret_cast<const u32x4*>(
                (const unsigned short*)Asrc + (size_t)mbase * 256);
            #pragma unroll
            for (int i = 0; i < 4; i++) areg[i] = src[tid + i * 256];
        } else {
            const f32x4* src = reinterpret_cast<const f32x4*>(
                (const float*)Asrc + (size_t)mbase * 256);
            #pragma unroll
            for (int i = 0; i < 4; i++) {
                int u = tid + i * 256;
                BFrag t; cvt8(t, src[2 * u], src[2 * u + 1]);
                areg[i] = t.q;
            }
        }
    };
    auto write_lds = [&](int buf) {
        #pragma unroll
        for (int i = 0; i < 4; i++) {
            int u = tid + i * 256;            // 0..1023 16B units
            int row = u >> 5, j = u & 31;
            int byte = row * 512 + ((j ^ (row & 7)) << 4);
            *reinterpret_cast<u32x4*>(&ldsA[buf][byte]) = areg[i];
        }
    };

    load_chunk(0);
    write_lds(0);
    if (MCHUNKS > 1) load_chunk(1);
    asm volatile("s_waitcnt lgkmcnt(0)\n\ts_barrier" ::: "memory");

    for (int c = 0; c < MCHUNKS; c++) {
        const int cur = c & 1;
        if (c + 1 < MCHUNKS) {
            write_lds(cur ^ 1);               // stage c+1 (regs loaded at c-1)
            if (c + 2 < MCHUNKS) load_chunk(c + 2);
        }

        f32x16 acc;
        #pragma unroll
        for (int i = 0; i < 16; i++) acc[i] = 0.0f;

        #pragma unroll
        for (int ks = 0; ks < 16; ks++) {
            int byte = cw * 512 + (((2 * ks + h) ^ (cw & 7)) << 4);
            BFrag a;
            a.q = *reinterpret_cast<const u32x4*>(&ldsA[cur][byte]);
            acc = __builtin_amdgcn_mfma_f32_32x32x16_bf16(a.v, bf[ks].v, acc, 0, 0, 0);
        }

        if (col < NCOLS) {
            const int rowb = (blockIdx.y * MCHUNKS + c) * 32 + h * 4;
            #pragma unroll
            for (int q = 0; q < 4; q++) {
                #pragma unroll
                for (int j = 0; j < 4; j++) {
                    float v = acc[q * 4 + j];
                    if (EPI == 1) v = fast_tanh(v + biasv);
                    C[(size_t)(rowb + q * 8 + j) * NCOLS + col] = v;
                }
            }
        }

        if (c + 1 < MCHUNKS)                  // writes visible + reads retired
            asm volatile("s_waitcnt lgkmcnt(0)\n\ts_barrier" ::: "memory");
    }
}

// K2: GRU gates. One block per batch row, thread = k. Writes h1 (f32, d_out
// tail) and h1 bf16 row-major (K3's A operand).
__global__ __launch_bounds__(256) void gru_gate(
    const int* __restrict__ inp, const float* __restrict__ hidden,
    const float* __restrict__ w_ih, const float* __restrict__ b_ih,
    const float* __restrict__ b_hh, const float* __restrict__ hproj,
    float* __restrict__ h1out, unsigned short* __restrict__ h1bf)
{
    const int b = blockIdx.x;
    const int k = threadIdx.x;
    const int c = inp[b];

    float xr = w_ih[(size_t)k * VOCAB + c]         + b_ih[k];
    float xz = w_ih[(size_t)(k + 256) * VOCAB + c] + b_ih[k + 256];
    float xn = w_ih[(size_t)(k + 512) * VOCAB + c] + b_ih[k + 512];

    float hr = hproj[b * GH + k]       + b_hh[k];
    float hz = hproj[b * GH + 256 + k] + b_hh[k + 256];
    float hn = hproj[b * GH + 512 + k] + b_hh[k + 512];

    float rg = fast_sigmoid(xr + hr);
    float zg = fast_sigmoid(xz + hz);
    float ng = fast_tanh(xn + rg * hn);
    float h0 = hidden[b * HID + k];
    float h1 = (1.0f - zg) * ng + zg * h0;

    h1out[b * HID + k] = h1;
    __bf16 hb = (__bf16)h1;
    h1bf[b * HID + k] = __builtin_bit_cast(unsigned short, hb);
}

extern "C" void kernel_launch(void* const* d_in, const int* in_sizes, int n_in,
                              void* d_out, int out_size, void* d_ws, size_t ws_size,
                              hipStream_t stream) {
    const int*   input  = (const int*)  d_in[0];
    // d_in[1] = target (unused)
    const float* hidden = (const float*)d_in[2];
    const float* w_ih   = (const float*)d_in[3];
    const float* w_hh   = (const float*)d_in[4];
    const float* b_ih   = (const float*)d_in[5];
    const float* b_hh   = (const float*)d_in[6];
    const float* w_out  = (const float*)d_in[7];
    const float* b_out  = (const float*)d_in[8];

    float* logit = (float*)d_out;                            // [512, 50000]
    float* h1    = (float*)d_out + (size_t)BATCH * VOCAB;    // [512, 256]

    float*          hproj = (float*)d_ws;                                   // 1.5 MB
    unsigned short* h1bf  = (unsigned short*)((char*)d_ws + (size_t)BATCH * GH * 4);

    // K1: hproj = h0 @ w_hh^T  (512 x 768) — grid (6,16), one 32-row chunk each
    dim3 g1(GH / 128, BATCH / 32);
    gemm32<0, GH, 1, 0><<<g1, 256, 0, stream>>>(hidden, w_hh, hproj, nullptr);

    // K2: gates -> h1 (f32) + h1bf (row-major bf16)
    gru_gate<<<BATCH, 256, 0, stream>>>(input, hidden, w_ih, b_ih, b_hh, hproj,
                                        h1, h1bf);

    // K3: logit = tanh(h1 @ w_out^T + b_out) — grid (391,2), 8 chunks each
    dim3 g3((VOCAB + 127) / 128, 2);
    gemm32<1, VOCAB, 8, 1><<<g3, 256, 0, stream>>>(h1bf, w_out, logit, b_out);
}

// Round 13
// 70.289 us; speedup vs baseline: 1.5726x; 1.0524x over previous
//
#include <hip/hip_runtime.h>
#include <hip/hip_bf16.h>

#define VOCAB 50000
#define HID   256
#define BATCH 512
#define GH    768   // 3*H

typedef __attribute__((ext_vector_type(8))) __bf16 bf16x8;
typedef __attribute__((ext_vector_type(4))) float f32x4;
typedef __attribute__((ext_vector_type(4))) unsigned int u32x4;

union BFrag {
    bf16x8 v;
    u32x4  q;
    __bf16 b[8];
};

__device__ __forceinline__ float fast_sigmoid(float x) {
    return 1.0f / (1.0f + __expf(-x));
}
__device__ __forceinline__ float fast_tanh(float x) {
    return 1.0f - 2.0f / (1.0f + __expf(2.0f * x));
}

// 8 consecutive f32 -> one bf16x8 fragment via native casts.
__device__ __forceinline__ void cvt8(BFrag& t, f32x4 lo, f32x4 hi) {
    t.b[0] = (__bf16)lo.x; t.b[1] = (__bf16)lo.y;
    t.b[2] = (__bf16)lo.z; t.b[3] = (__bf16)lo.w;
    t.b[4] = (__bf16)hi.x; t.b[5] = (__bf16)hi.y;
    t.b[6] = (__bf16)hi.z; t.b[7] = (__bf16)hi.w;
}

// 16B global -> LDS DMA (no VGPR round-trip). LDS dest: wave-uniform base +
// lane*16 (linear); swizzle handled by pre-swizzling the GLOBAL source image.
__device__ __forceinline__ void gload_lds16(const void* g, void* l) {
    __builtin_amdgcn_global_load_lds(
        (const __attribute__((address_space(1))) unsigned int*)g,
        (__attribute__((address_space(3))) unsigned int*)l, 16, 0, 0);
}

// ---------------------------------------------------------------------------
// Swizzled A image (per 32-row chunk, 16 KB):
//   byte(row, k) = row*512 + ((j ^ (row&7)) << 4) + e*2,  j = k>>3, e = k&7
// ds_read of fragment (arow, kk, g) = arow*512 + (((kk*4+g) ^ (arow&7)) << 4)
// (R1/R8-proven balanced-bank pattern).
// ---------------------------------------------------------------------------

// K3: logit = tanh(A @ w_out^T + b_out). One block per 64-col tile: B fetched
// from HBM exactly once (XCD-proof). A (pre-swizzled image, 256 KB,
// L2-resident) streamed in 32-row chunks via global_load_lds into
// double-buffered LDS. Counted vmcnt(8) barrier: 4 DMA + 8 stores in flight,
// never drained to 0 in-loop. Tail block: lanes clamp to col VOCAB-1 and
// store redundantly-identical values (keeps store count wave-uniform).
__global__ __launch_bounds__(256, 4) void gemm_dma(
    const char* __restrict__ Aswz, const float* __restrict__ Bm,
    float* __restrict__ C, const float* __restrict__ bias, int mChunks)
{
    __shared__ char ldsA[2][16384];           // 2 x (32 rows x 256 bf16), swizzled

    const int tid  = threadIdx.x;
    const int wid  = tid >> 6;
    const int lane = tid & 63;
    const int r    = lane & 15;
    const int g    = lane >> 4;
    const int col  = blockIdx.x * 64 + wid * 16 + r;
    const int bcol = col < VOCAB ? col : (VOCAB - 1);   // clamp: see header

    // ---- B fragments: 8 per wave (32 VGPR), NT load + convert once ----
    BFrag bf[8];
    {
        const f32x4* wrow = reinterpret_cast<const f32x4*>(Bm + (size_t)bcol * 256);
        #pragma unroll
        for (int kk = 0; kk < 8; kk++) {
            f32x4 lo = __builtin_nontemporal_load(&wrow[kk * 8 + g * 2]);
            f32x4 hi = __builtin_nontemporal_load(&wrow[kk * 8 + g * 2 + 1]);
            cvt8(bf[kk], lo, hi);
        }
    }
    #pragma unroll
    for (int kk = 0; kk < 8; kk++)
        asm volatile("" : "+v"(bf[kk].q));    // keep resident (R5 lesson)
    const float biasv = bias[bcol];

    auto dma = [&](int c, int buf) {          // 4 x 16B DMA per thread-slot
        const char* src = Aswz + (size_t)c * 16384 + wid * 1024 + lane * 16;
        char* dst = &ldsA[buf][wid * 1024];
        #pragma unroll
        for (int i = 0; i < 4; i++)
            gload_lds16(src + i * 4096, dst + i * 4096);
    };

    dma(0, 0);
    asm volatile("s_waitcnt vmcnt(0)" ::: "memory");
    __builtin_amdgcn_s_barrier();

    for (int c = 0; c < mChunks; c++) {
        const int cur = c & 1;
        if (c + 1 < mChunks) dma(c + 1, cur ^ 1);
        __builtin_amdgcn_sched_barrier(0);    // pin DMA issue before compute/stores

        f32x4 acc0 = (f32x4){0.f, 0.f, 0.f, 0.f};
        f32x4 acc1 = (f32x4){0.f, 0.f, 0.f, 0.f};

        #pragma unroll
        for (int kk = 0; kk < 8; kk++) {
            const int s0 = r * 512 + ((((kk << 2) + g) ^ (r & 7)) << 4);
            BFrag a0, a1;
            a0.q = *reinterpret_cast<const u32x4*>(&ldsA[cur][s0]);          // row r
            a1.q = *reinterpret_cast<const u32x4*>(&ldsA[cur][s0 + 8192]);   // row 16+r
            acc0 = __builtin_amdgcn_mfma_f32_16x16x32_bf16(a0.v, bf[kk].v, acc0, 0, 0, 0);
            acc1 = __builtin_amdgcn_mfma_f32_16x16x32_bf16(a1.v, bf[kk].v, acc1, 0, 0, 0);
        }

        // epilogue: 8 unconditional stores (uniform vmcnt count)
        const int rowb = c * 32 + g * 4;
        #pragma unroll
        for (int j = 0; j < 4; j++) {
            float v0 = fast_tanh(acc0[j] + biasv);
            float v1 = fast_tanh(acc1[j] + biasv);
            C[(size_t)(rowb + j) * VOCAB + bcol]      = v0;
            C[(size_t)(rowb + 16 + j) * VOCAB + bcol] = v1;
        }

        if (c + 1 < mChunks) {
            // drain the 4 DMAs (+older store remnants); leave this chunk's
            // 8 stores in flight — never vmcnt(0) in-loop (T4)
            asm volatile("s_waitcnt vmcnt(8)" ::: "memory");
            __builtin_amdgcn_s_barrier();
        }
    }
}

// K1: hproj = h0 @ w_hh^T  (512 x 768, K=256). Small; R8-style reg-staged
// swizzled LDS, one chunk of 32 rows per block. grid (12, 16).
__global__ __launch_bounds__(256, 4) void gemm_h(
    const float* __restrict__ A, const float* __restrict__ Bm,
    float* __restrict__ C)
{
    __shared__ char ldsA[16384];              // 32 rows x 256 bf16, swizzled

    const int tid  = threadIdx.x;
    const int wid  = tid >> 6;
    const int lane = tid & 63;
    const int r    = lane & 15;
    const int g    = lane >> 4;
    const int col  = blockIdx.x * 64 + wid * 16 + r;    // < 768 always
    const int mbase = blockIdx.y * 32;

    BFrag bf[8];
    {
        const f32x4* wrow = reinterpret_cast<const f32x4*>(Bm + (size_t)col * 256);
        #pragma unroll
        for (int kk = 0; kk < 8; kk++)
            cvt8(bf[kk], wrow[kk * 8 + g * 2], wrow[kk * 8 + g * 2 + 1]);
    }

    // stage A chunk (f32 -> bf16, swizzled)
    {
        const f32x4* src = reinterpret_cast<const f32x4*>(A + (size_t)mbase * 256);
        #pragma unroll
        for (int i = 0; i < 4; i++) {
            int u = tid + i * 256;            // 0..1023 16B units
            int row = u >> 5, jj = u & 31;
            BFrag t; cvt8(t, src[2 * u], src[2 * u + 1]);
            int byte = row * 512 + ((jj ^ (row & 7)) << 4);
            *reinterpret_cast<u32x4*>(&ldsA[byte]) = t.q;
        }
    }
    __syncthreads();

    f32x4 acc0 = (f32x4){0.f, 0.f, 0.f, 0.f};
    f32x4 acc1 = (f32x4){0.f, 0.f, 0.f, 0.f};
    #pragma unroll
    for (int kk = 0; kk < 8; kk++) {
        const int s0 = r * 512 + ((((kk << 2) + g) ^ (r & 7)) << 4);
        BFrag a0, a1;
        a0.q = *reinterpret_cast<const u32x4*>(&ldsA[s0]);
        a1.q = *reinterpret_cast<const u32x4*>(&ldsA[s0 + 8192]);
        acc0 = __builtin_amdgcn_mfma_f32_16x16x32_bf16(a0.v, bf[kk].v, acc0, 0, 0, 0);
        acc1 = __builtin_amdgcn_mfma_f32_16x16x32_bf16(a1.v, bf[kk].v, acc1, 0, 0, 0);
    }

    const int rowb = mbase + g * 4;
    #pragma unroll
    for (int j = 0; j < 4; j++) {
        C[(size_t)(rowb + j) * GH + col]      = acc0[j];
        C[(size_t)(rowb + 16 + j) * GH + col] = acc1[j];
    }
}

// K2: GRU gates. One block per batch row, thread = k. Writes h1 (f32, d_out
// tail) and h1 bf16 in the SWIZZLED-LDS-IMAGE order (K3's DMA source).
__global__ __launch_bounds__(256) void gru_gate(
    const int* __restrict__ inp, const float* __restrict__ hidden,
    const float* __restrict__ w_ih, const float* __restrict__ b_ih,
    const float* __restrict__ b_hh, const float* __restrict__ hproj,
    float* __restrict__ h1out, char* __restrict__ h1swz)
{
    const int b = blockIdx.x;
    const int k = threadIdx.x;
    const int c = inp[b];

    float xr = w_ih[(size_t)k * VOCAB + c]         + b_ih[k];
    float xz = w_ih[(size_t)(k + 256) * VOCAB + c] + b_ih[k + 256];
    float xn = w_ih[(size_t)(k + 512) * VOCAB + c] + b_ih[k + 512];

    float hr = hproj[b * GH + k]       + b_hh[k];
    float hz = hproj[b * GH + 256 + k] + b_hh[k + 256];
    float hn = hproj[b * GH + 512 + k] + b_hh[k + 512];

    float rg = fast_sigmoid(xr + hr);
    float zg = fast_sigmoid(xz + hz);
    float ng = fast_tanh(xn + rg * hn);
    float h0 = hidden[b * HID + k];
    float h1 = (1.0f - zg) * ng + zg * h0;

    h1out[b * HID + k] = h1;

    // swizzled-image write: chunk = b>>5, row = b&31, unit j = k>>3, e = k&7
    const int row = b & 31, j = k >> 3, e = k & 7;
    size_t byte = (size_t)(b >> 5) * 16384 + row * 512
                + ((j ^ (row & 7)) << 4) + e * 2;
    __bf16 hb = (__bf16)h1;
    *reinterpret_cast<unsigned short*>(h1swz + byte) =
        __builtin_bit_cast(unsigned short, hb);
}

extern "C" void kernel_launch(void* const* d_in, const int* in_sizes, int n_in,
                              void* d_out, int out_size, void* d_ws, size_t ws_size,
                              hipStream_t stream) {
    const int*   input  = (const int*)  d_in[0];
    // d_in[1] = target (unused)
    const float* hidden = (const float*)d_in[2];
    const float* w_ih   = (const float*)d_in[3];
    const float* w_hh   = (const float*)d_in[4];
    const float* b_ih   = (const float*)d_in[5];
    const float* b_hh   = (const float*)d_in[6];
    const float* w_out  = (const float*)d_in[7];
    const float* b_out  = (const float*)d_in[8];

    float* logit = (float*)d_out;                            // [512, 50000]
    float* h1    = (float*)d_out + (size_t)BATCH * VOCAB;    // [512, 256]

    char*  h1swz = (char*)d_ws;                              // 256 KB swizzled image
    float* hproj = (float*)((char*)d_ws + 256 * 1024);       // 1.5 MB

    // K1: hproj = h0 @ w_hh^T — grid (12, 16)
    dim3 g1(GH / 64, BATCH / 32);
    gemm_h<<<g1, 256, 0, stream>>>(hidden, w_hh, hproj);

    // K2: gates -> h1 (f32) + h1swz (swizzled bf16 image)
    gru_gate<<<BATCH, 256, 0, stream>>>(input, hidden, w_ih, b_ih, b_hh, hproj,
                                        h1, h1swz);

    // K3: logit = tanh(h1 @ w_out^T + b_out) — 782 col-tile blocks, 16 chunks
    dim3 g3((VOCAB + 63) / 64, 1);
    gemm_dma<<<g3, 256, 0, stream>>>(h1swz, w_out, logit, b_out, 16);
}

// Round 14
// 67.476 us; speedup vs baseline: 1.6382x; 1.0417x over previous
//
#include <hip/hip_runtime.h>
#include <hip/hip_bf16.h>

#define VOCAB 50000
#define HID   256
#define BATCH 512
#define GH    768   // 3*H

typedef __attribute__((ext_vector_type(8))) __bf16 bf16x8;
typedef __attribute__((ext_vector_type(4))) float f32x4;
typedef __attribute__((ext_vector_type(4))) unsigned int u32x4;

union BFrag {
    bf16x8 v;
    u32x4  q;
    __bf16 b[8];
};

__device__ __forceinline__ float fast_sigmoid(float x) {
    return 1.0f / (1.0f + __expf(-x));
}
__device__ __forceinline__ float fast_tanh(float x) {
    return 1.0f - 2.0f / (1.0f + __expf(2.0f * x));
}

// 8 consecutive f32 -> one bf16x8 fragment via native casts.
__device__ __forceinline__ void cvt8(BFrag& t, f32x4 lo, f32x4 hi) {
    t.b[0] = (__bf16)lo.x; t.b[1] = (__bf16)lo.y;
    t.b[2] = (__bf16)lo.z; t.b[3] = (__bf16)lo.w;
    t.b[4] = (__bf16)hi.x; t.b[5] = (__bf16)hi.y;
    t.b[6] = (__bf16)hi.z; t.b[7] = (__bf16)hi.w;
}

// K3: logit = tanh(h1 @ w_out^T + b_out), SWAPPED-OPERAND epilogue.
// Structure = R8 (61.2us best): one block per 64-col tile (w_out fetched from
// HBM exactly once, NT), h1 streamed in 32-row chunks through double-buffered
// swizzled LDS, ONE lgkm-only s_barrier per chunk, stores never drained.
// Change vs R8: mfma(A=w_out_frag, B=h1_frag) -> D rows = vocab cols, D cols
// = batch rows; thread (r,g) holds batch row r / vocab cols vcol0..vcol0+3
// -> epilogue is 2 dwordx4 stores per chunk (was 8 scalar dwords).
__global__ __launch_bounds__(256, 4) void gemm_swp(
    const unsigned short* __restrict__ Abf, const float* __restrict__ Bm,
    float* __restrict__ C, const float* __restrict__ bias, int mChunks)
{
    __shared__ char ldsA[2][16384];           // 2 x (32 rows x 256 bf16), swizzled

    const int tid  = threadIdx.x;
    const int wid  = tid >> 6;
    const int lane = tid & 63;
    const int r    = lane & 15;
    const int g    = lane >> 4;
    // lane's resident w_out row (feeds MFMA A-operand: A-row = lane&15)
    const int wcol = blockIdx.x * 64 + wid * 16 + r;
    const int bw   = wcol < VOCAB ? wcol : (VOCAB - 1);

    // ---- w_out fragments: 8 per wave (32 VGPR), NT load + convert, pin ----
    BFrag bf[8];
    {
        const f32x4* wrow = reinterpret_cast<const f32x4*>(Bm + (size_t)bw * 256);
        #pragma unroll
        for (int kk = 0; kk < 8; kk++) {
            f32x4 lo = __builtin_nontemporal_load(&wrow[kk * 8 + g * 2]);
            f32x4 hi = __builtin_nontemporal_load(&wrow[kk * 8 + g * 2 + 1]);
            cvt8(bf[kk], lo, hi);
        }
    }
    #pragma unroll
    for (int kk = 0; kk < 8; kk++)
        asm volatile("" : "+v"(bf[kk].q));    // keep resident (R5 lesson)

    // this thread's 4 output vocab cols (D rows g*4..g*4+3) + their biases
    const int vcol0   = blockIdx.x * 64 + wid * 16 + g * 4;
    const bool storeok = (vcol0 + 3 < VOCAB);            // wave-uniform in practice
    const int bvc     = storeok ? vcol0 : (VOCAB - 4);
    const f32x4 b4    = *reinterpret_cast<const f32x4*>(bias + bvc);

    // ---- h1 staging: loads lead by 2 chunks, ds_writes by 1 (R8 pattern) ----
    u32x4 areg[4];
    auto load_chunk = [&](int c) {
        const u32x4* src = reinterpret_cast<const u32x4*>(Abf + (size_t)c * 32 * 256);
        #pragma unroll
        for (int i = 0; i < 4; i++) areg[i] = src[tid + i * 256];
    };
    auto write_lds = [&](int buf) {
        #pragma unroll
        for (int i = 0; i < 4; i++) {
            int u = tid + i * 256;            // 0..1023 16B units
            int row = u >> 5, j = u & 31;
            int byte = row * 512 + ((j ^ (row & 7)) << 4);
            *reinterpret_cast<u32x4*>(&ldsA[buf][byte]) = areg[i];
        }
    };

    load_chunk(0);
    write_lds(0);
    if (mChunks > 1) load_chunk(1);
    asm volatile("s_waitcnt lgkmcnt(0)\n\ts_barrier" ::: "memory");

    for (int c = 0; c < mChunks; c++) {
        const int cur = c & 1;
        if (c + 1 < mChunks) {
            write_lds(cur ^ 1);               // stage c+1 (regs loaded at c-1)
            if (c + 2 < mChunks) load_chunk(c + 2);
        }

        f32x4 acc0 = (f32x4){0.f, 0.f, 0.f, 0.f};   // batch rows c*32 + r
        f32x4 acc1 = (f32x4){0.f, 0.f, 0.f, 0.f};   // batch rows c*32 + 16 + r

        #pragma unroll
        for (int kk = 0; kk < 8; kk++) {
            const int s0 = r * 512 + ((((kk << 2) + g) ^ (r & 7)) << 4);
            BFrag a0, a1;
            a0.q = *reinterpret_cast<const u32x4*>(&ldsA[cur][s0]);          // rows 0-15
            a1.q = *reinterpret_cast<const u32x4*>(&ldsA[cur][s0 + 8192]);   // rows 16-31
            // SWAPPED: w_out as A-operand, h1 as B-operand
            acc0 = __builtin_amdgcn_mfma_f32_16x16x32_bf16(bf[kk].v, a0.v, acc0, 0, 0, 0);
            acc1 = __builtin_amdgcn_mfma_f32_16x16x32_bf16(bf[kk].v, a1.v, acc1, 0, 0, 0);
        }

        // epilogue: 2 x dwordx4 (16B) stores -> 1KB per wave-instruction
        if (storeok) {
            const int row0 = c * 32 + r;
            f32x4 v0, v1;
            #pragma unroll
            for (int j = 0; j < 4; j++) {
                v0[j] = fast_tanh(acc0[j] + b4[j]);
                v1[j] = fast_tanh(acc1[j] + b4[j]);
            }
            *reinterpret_cast<f32x4*>(&C[(size_t)row0 * VOCAB + vcol0])        = v0;
            *reinterpret_cast<f32x4*>(&C[(size_t)(row0 + 16) * VOCAB + vcol0]) = v1;
        }

        if (c + 1 < mChunks)
            asm volatile("s_waitcnt lgkmcnt(0)\n\ts_barrier" ::: "memory");
    }
}

// K1: hproj = h0 @ w_hh^T  (512 x 768, K=256). R13-proven small kernel.
__global__ __launch_bounds__(256, 4) void gemm_h(
    const float* __restrict__ A, const float* __restrict__ Bm,
    float* __restrict__ C)
{
    __shared__ char ldsA[16384];              // 32 rows x 256 bf16, swizzled

    const int tid  = threadIdx.x;
    const int wid  = tid >> 6;
    const int lane = tid & 63;
    const int r    = lane & 15;
    const int g    = lane >> 4;
    const int col  = blockIdx.x * 64 + wid * 16 + r;    // < 768 always
    const int mbase = blockIdx.y * 32;

    BFrag bf[8];
    {
        const f32x4* wrow = reinterpret_cast<const f32x4*>(Bm + (size_t)col * 256);
        #pragma unroll
        for (int kk = 0; kk < 8; kk++)
            cvt8(bf[kk], wrow[kk * 8 + g * 2], wrow[kk * 8 + g * 2 + 1]);
    }

    {
        const f32x4* src = reinterpret_cast<const f32x4*>(A + (size_t)mbase * 256);
        #pragma unroll
        for (int i = 0; i < 4; i++) {
            int u = tid + i * 256;
            int row = u >> 5, jj = u & 31;
            BFrag t; cvt8(t, src[2 * u], src[2 * u + 1]);
            int byte = row * 512 + ((jj ^ (row & 7)) << 4);
            *reinterpret_cast<u32x4*>(&ldsA[byte]) = t.q;
        }
    }
    __syncthreads();

    f32x4 acc0 = (f32x4){0.f, 0.f, 0.f, 0.f};
    f32x4 acc1 = (f32x4){0.f, 0.f, 0.f, 0.f};
    #pragma unroll
    for (int kk = 0; kk < 8; kk++) {
        const int s0 = r * 512 + ((((kk << 2) + g) ^ (r & 7)) << 4);
        BFrag a0, a1;
        a0.q = *reinterpret_cast<const u32x4*>(&ldsA[s0]);
        a1.q = *reinterpret_cast<const u32x4*>(&ldsA[s0 + 8192]);
        acc0 = __builtin_amdgcn_mfma_f32_16x16x32_bf16(a0.v, bf[kk].v, acc0, 0, 0, 0);
        acc1 = __builtin_amdgcn_mfma_f32_16x16x32_bf16(a1.v, bf[kk].v, acc1, 0, 0, 0);
    }

    const int rowb = mbase + g * 4;
    #pragma unroll
    for (int j = 0; j < 4; j++) {
        C[(size_t)(rowb + j) * GH + col]      = acc0[j];
        C[(size_t)(rowb + 16 + j) * GH + col] = acc1[j];
    }
}

// K2: GRU gates. One block per batch row, thread = k. Writes h1 (f32, d_out
// tail) and h1 bf16 row-major (K3's streamed operand).
__global__ __launch_bounds__(256) void gru_gate(
    const int* __restrict__ inp, const float* __restrict__ hidden,
    const float* __restrict__ w_ih, const float* __restrict__ b_ih,
    const float* __restrict__ b_hh, const float* __restrict__ hproj,
    float* __restrict__ h1out, unsigned short* __restrict__ h1bf)
{
    const int b = blockIdx.x;
    const int k = threadIdx.x;
    const int c = inp[b];

    float xr = w_ih[(size_t)k * VOCAB + c]         + b_ih[k];
    float xz = w_ih[(size_t)(k + 256) * VOCAB + c] + b_ih[k + 256];
    float xn = w_ih[(size_t)(k + 512) * VOCAB + c] + b_ih[k + 512];

    float hr = hproj[b * GH + k]       + b_hh[k];
    float hz = hproj[b * GH + 256 + k] + b_hh[k + 256];
    float hn = hproj[b * GH + 512 + k] + b_hh[k + 512];

    float rg = fast_sigmoid(xr + hr);
    float zg = fast_sigmoid(xz + hz);
    float ng = fast_tanh(xn + rg * hn);
    float h0 = hidden[b * HID + k];
    float h1 = (1.0f - zg) * ng + zg * h0;

    h1out[b * HID + k] = h1;
    __bf16 hb = (__bf16)h1;
    h1bf[b * HID + k] = __builtin_bit_cast(unsigned short, hb);
}

extern "C" void kernel_launch(void* const* d_in, const int* in_sizes, int n_in,
                              void* d_out, int out_size, void* d_ws, size_t ws_size,
                              hipStream_t stream) {
    const int*   input  = (const int*)  d_in[0];
    // d_in[1] = target (unused)
    const float* hidden = (const float*)d_in[2];
    const float* w_ih   = (const float*)d_in[3];
    const float* w_hh   = (const float*)d_in[4];
    const float* b_ih   = (const float*)d_in[5];
    const float* b_hh   = (const float*)d_in[6];
    const float* w_out  = (const float*)d_in[7];
    const float* b_out  = (const float*)d_in[8];

    float* logit = (float*)d_out;                            // [512, 50000]
    float* h1    = (float*)d_out + (size_t)BATCH * VOCAB;    // [512, 256]

    float*          hproj = (float*)d_ws;                                   // 1.5 MB
    unsigned short* h1bf  = (unsigned short*)((char*)d_ws + (size_t)BATCH * GH * 4);

    // K1: hproj = h0 @ w_hh^T — grid (12, 16)
    dim3 g1(GH / 64, BATCH / 32);
    gemm_h<<<g1, 256, 0, stream>>>(hidden, w_hh, hproj);

    // K2: gates -> h1 (f32) + h1bf (row-major bf16)
    gru_gate<<<BATCH, 256, 0, stream>>>(input, hidden, w_ih, b_ih, b_hh, hproj,
                                        h1, h1bf);

    // K3: logit = tanh(h1 @ w_out^T + b_out) — 782 col-tile blocks, 16 chunks
    dim3 g3((VOCAB + 63) / 64, 1);
    gemm_swp<<<g3, 256, 0, stream>>>(h1bf, w_out, logit, b_out, 16);
}